// Round 1
// baseline (122.980 us; speedup 1.0000x reference)
//
#include <hip/hip_runtime.h>

#define NEG_INF (-__builtin_huge_valf())
#define NEG_INF_BITS 0xFF800000

#define CCH    8                 // channels staged per chunk
#define HB     4                 // output h rows per block tile
#define ROWS   (HB + 2)          // 6 (h halo)
#define NROW   (CCH * ROWS)      // 48 staged rows
#define XSTR   64                // xs row stride (floats) — pure data, no edge array
#define SLOTS  3                 // NROW rows * 16 float4 / 256 threads
#define OW     4                 // o-pairs (waves) per block

// Neighbor fetch via DPP within each 16-lane row (wg axis).
// update_dpp with bound_ctrl=false leaves invalid-source lanes at `old`:
// old = -inf IS the W padding at wg==0 (row_shr:1) / wg==15 (row_shl:1).
template <int CTRL>
__device__ __forceinline__ float dpp_neighbor(float v) {
    return __int_as_float(__builtin_amdgcn_update_dpp(
        (int)NEG_INF_BITS, __float_as_int(v), CTRL, 0xF, 0xF, false));
}

// 4 waves per block, each wave owns one o-pair; all waves share one x staging.
// Grid (16,8,8) = 1024 blocks = exactly 4 blocks/CU = 16 waves/CU.
// LDS: 48 rows x 64 floats = 12288 B (3 KB/wave vs 10 KB/wave before).
__global__ __launch_bounds__(256, 4)
void maxplus_conv2d_kernel(const float* __restrict__ x,
                           const float* __restrict__ kern,
                           float* __restrict__ out) {
    __shared__ float xs[NROW * XSTR];

    const int tid  = threadIdx.x;                              // 0..255
    const int lane = tid & 63;
    const int wave = __builtin_amdgcn_readfirstlane(tid >> 6); // 0..3, force SGPR
    const int wg   = lane & 15;                                // w-group in wave
    const int hr   = lane >> 4;                                // 0..3 output row
    const int w0   = wg << 2;

    const int h_base = blockIdx.x * HB;
    const int b      = blockIdx.y;
    const int o0     = blockIdx.z * (OW * 2) + wave * 2;       // wave's o-pair

    // h-halo rows outside [0,64) stay -inf forever; only edge tiles need init.
    if (h_base == 0 || h_base == 60) {
        for (int k = tid; k < NROW * XSTR; k += 256)
            xs[k] = NEG_INF;
    }

    // ---- staging slots: 48 rows x 16 float4 = 768 = exactly 3 per thread ----
    const float* xb = x + (size_t)b * (64 * 64 * 64);
    const float* gsrc[SLOTS];
    float*       xdst[SLOTS];
    bool         sval[SLOTS];
#pragma unroll
    for (int s = 0; s < SLOTS; ++s) {
        int idx   = s * 256 + tid;      // 0..767
        int rowid = idx >> 4;           // 0..47
        int wgp   = idx & 15;
        int cl    = rowid / ROWS;
        int r     = rowid - cl * ROWS;
        int gh    = h_base + r - 1;     // -1..64
        bool v    = (unsigned)gh < 64u;
        gsrc[s] = xb + ((size_t)cl * 64 + (v ? gh : 0)) * 64 + wgp * 4;
        xdst[s] = &xs[rowid * XSTR + wgp * 4];   // aligned ds_write_b128
        sval[s] = v;                              // chunk-invariant
    }

    float acc[2][4];
#pragma unroll
    for (int oo = 0; oo < 2; ++oo)
#pragma unroll
        for (int wi = 0; wi < 4; ++wi)
            acc[oo][wi] = NEG_INF;

    // prefetch chunk 0
    float4 R[SLOTS];
#pragma unroll
    for (int s = 0; s < SLOTS; ++s) R[s] = *(const float4*)gsrc[s];

    const float* kpw = kern + (size_t)o0 * (64 * 9);

#pragma unroll 1
    for (int cc = 0; cc < 64; cc += CCH) {
        __syncthreads();                 // WAR: prior chunk's reads done
#pragma unroll
        for (int s = 0; s < SLOTS; ++s)
            if (sval[s]) *(float4*)xdst[s] = R[s];
        __syncthreads();                 // RAW: writes visible to all waves

        if (cc + CCH < 64) {             // next-chunk prefetch rides under compute
#pragma unroll
            for (int s = 0; s < SLOTS; ++s) {
                gsrc[s] += CCH * 64 * 64;
                R[s] = *(const float4*)gsrc[s];
            }
        }

#pragma unroll 1
        for (int half = 0; half < 2; ++half) {
            // wave-uniform taps -> grouped s_loads; 72 floats fits SGPR budget
            float kv[4][2][9];
#pragma unroll
            for (int cl = 0; cl < 4; ++cl)
#pragma unroll
                for (int oo = 0; oo < 2; ++oo) {
                    const float* kp = kpw + ((size_t)oo * 64 + (cc + half * 4 + cl)) * 9;
#pragma unroll
                    for (int t = 0; t < 9; ++t) kv[cl][oo][t] = kp[t];
                }

#pragma unroll
            for (int cl = 0; cl < 4; ++cl) {
                const int rbase = (half * 4 + cl) * ROWS + hr;
                float xv[3][6];
#pragma unroll
                for (int r = 0; r < 3; ++r) {
                    float4 m = *(const float4*)(&xs[(rbase + r) * XSTR + w0]);
                    xv[r][0] = dpp_neighbor<0x111>(m.w);  // row_shr:1 -> lane-1 (left edge)
                    xv[r][1] = m.x; xv[r][2] = m.y; xv[r][3] = m.z; xv[r][4] = m.w;
                    xv[r][5] = dpp_neighbor<0x101>(m.x);  // row_shl:1 -> lane+1 (right edge)
                }

#pragma unroll
                for (int oo = 0; oo < 2; ++oo) {
                    const float* k9 = kv[cl][oo];
#pragma unroll
                    for (int wi = 0; wi < 4; ++wi) {
                        float m = acc[oo][wi];
                        // paired -> v_max3_f32: 9 add + 4 max3 + 1 max per out per c
                        float t0 = xv[0][wi + 0] + k9[0];
                        float t1 = xv[0][wi + 1] + k9[1];
                        m = fmaxf(m, fmaxf(t0, t1));
                        t0 = xv[0][wi + 2] + k9[2];
                        t1 = xv[1][wi + 0] + k9[3];
                        m = fmaxf(m, fmaxf(t0, t1));
                        t0 = xv[1][wi + 1] + k9[4];
                        t1 = xv[1][wi + 2] + k9[5];
                        m = fmaxf(m, fmaxf(t0, t1));
                        t0 = xv[2][wi + 0] + k9[6];
                        t1 = xv[2][wi + 1] + k9[7];
                        m = fmaxf(m, fmaxf(t0, t1));
                        m = fmaxf(m, xv[2][wi + 2] + k9[8]);
                        acc[oo][wi] = m;
                    }
                }
            }
        }
    }

    const int h = h_base + hr;
#pragma unroll
    for (int oo = 0; oo < 2; ++oo) {
        float4 v = make_float4(acc[oo][0], acc[oo][1], acc[oo][2], acc[oo][3]);
        *(float4*)(out + ((((size_t)b * 64 + (o0 + oo)) * 64 + h) * 64 + w0)) = v;
    }
}

extern "C" void kernel_launch(void* const* d_in, const int* in_sizes, int n_in,
                              void* d_out, int out_size, void* d_ws, size_t ws_size,
                              hipStream_t stream) {
    const float* x    = (const float*)d_in[0];   // [8,64,64,64]
    const float* kern = (const float*)d_in[1];   // [64,64,3,3]
    float* out = (float*)d_out;                  // [8,64,64,64]

    dim3 grid(16, 8, 8);    // h-tiles, b, o-octets (4 waves x o-pair each)
    dim3 block(256);
    maxplus_conv2d_kernel<<<grid, block, 0, stream>>>(x, kern, out);
}